// Round 7
// baseline (430.681 us; speedup 1.0000x reference)
//
#include <hip/hip_runtime.h>

// Axial multi-dimensional self-attention, B=1, C=32, D=32, H=128, W=128, fp32.
// Algebra: S = X^T M X (M = scale*Wq^T*Wk), P = softmax_rows(S), U = X P^T,
//          out = (Wo Wv) (U_D + U_H + U_W) + x.
// kinit: M = scale*Wq^T*Wk and Ps = Wo*Wv, split-bf16, into d_ws (global,
//        L2-resident; all blocks load MFMA fragments directly from it).
// kw/kh: MFMA slice engine (split-bf16 scores, bf16 P), 3 blocks/CU.
// kd: MFMA L=32 engine fused with projection epilogue + residual.

#define C_ 32
#define D_ 32
#define H_ 128
#define W_ 128
#define SC (D_*H_*W_)   // 524288
#define SD (H_*W_)      // 16384
#define SH (W_)         // 128
#define SCALE 0.17677669529663687f

typedef __attribute__((ext_vector_type(8))) short short8;   // 8 bf16 (4 VGPR)
typedef __attribute__((ext_vector_type(4))) short short4v;  // 4 bf16
typedef __attribute__((ext_vector_type(2))) short short2v;  // 2 bf16
typedef __attribute__((ext_vector_type(4))) float f32x4;

#define MFMA16(a,b,c) __builtin_amdgcn_mfma_f32_16x16x32_bf16(a,b,c,0,0,0)

__device__ __forceinline__ int xcd_swz(int bid, int nwg) {
    int chunk = nwg >> 3;
    return (bid & 7) * chunk + (bid >> 3);
}
__device__ __forceinline__ short bf16_trunc(float f) {
    return (short)(__float_as_uint(f) >> 16);
}
__device__ __forceinline__ short bf16_rtne(float f) {
    unsigned u = __float_as_uint(f);
    unsigned r = u + 0x7FFFu + ((u >> 16) & 1u);
    return (short)(r >> 16);
}
__device__ __forceinline__ float bf16_tof(short s) {
    return __uint_as_float(((unsigned)(unsigned short)s) << 16);
}
// two ds_read_b64 (8B-aligned) -> short8
__device__ __forceinline__ short8 ld8_b64x2(const short* p) {
    short4v a = *(const short4v*)p;
    short4v b = *(const short4v*)(p + 4);
    short8 o;
    o[0]=a[0]; o[1]=a[1]; o[2]=a[2]; o[3]=a[3];
    o[4]=b[0]; o[5]=b[1]; o[6]=b[2]; o[7]=b[3];
    return o;
}

// ---------------- weight precompute: ws = [Mh|Ml|Ph|Pl], 1024 shorts each ---
__global__ __launch_bounds__(256) void kinit_kernel(
        const float* __restrict__ Wq, const float* __restrict__ Wk,
        const float* __restrict__ Wv, const float* __restrict__ Wo,
        short* __restrict__ ws) {
    int o = blockIdx.x * 256 + threadIdx.x;   // 4 blocks -> o in [0,1024)
    int a = o >> 5, b = o & 31;
    float m = 0.f, p = 0.f;
    #pragma unroll
    for (int k = 0; k < 32; ++k) {
        m += Wq[k*32+a] * Wk[k*32+b];   // M[a][b]
        p += Wo[a*32+k] * Wv[k*32+b];   // Ps[a][b]
    }
    m *= SCALE;
    short mh = bf16_trunc(m);
    ws[o]        = mh;
    ws[1024 + o] = bf16_trunc(m - bf16_tof(mh));
    short ph = bf16_trunc(p);
    ws[2048 + o] = ph;
    ws[3072 + o] = bf16_trunc(p - bf16_tof(ph));
}

// ---------------- MFMA slice engine: one L=128 slice (kw/kh) ----------------
// LDS R region (36864 B) = [Xf fp32 32x128 | Tt_h 128x40 | Tt_l 128x40],
// later overlaid by P bf16 [128][136] (34816 B). Xh bf16 [32][136] separate.
// Entry: Xf fp32 [c][u] and Xh bf16 [c][u] staged + barrier done.
#define TT_STRIDE 40
#define XH_STRIDE 136
#define P_STRIDE  136
#define R_BYTES   36864

__device__ __forceinline__ void slice_engine(
        const float* Xf, const short8 mah[2], const short8 mal[2],
        short* Tt_h, short* Tt_l, short* P, short* Xh,
        f32x4 uacc[2][2])
{
    const int t = threadIdx.x;
    const int wv = t >> 6, l = t & 63, hi = l >> 4, r = l & 15;
    const int qb = wv * 32;

    // split-bf16 X column fragments (T-B and S-A roles share one layout)
    short8 xh_[2], xl_[2];
    #pragma unroll
    for (int nt = 0; nt < 2; ++nt) {
        int u = qb + nt*16 + r;
        #pragma unroll
        for (int j = 0; j < 8; ++j) {
            float f = Xf[(hi*8 + j)*128 + u];
            short h = bf16_trunc(f);
            xh_[nt][j] = h; xl_[nt][j] = bf16_trunc(f - bf16_tof(h));
        }
    }

    // T = M*X (3-MFMA split); wave owns u in [qb, qb+32)
    f32x4 tacc[2][2] = {};
    #pragma unroll
    for (int nt = 0; nt < 2; ++nt) {
        #pragma unroll
        for (int mt = 0; mt < 2; ++mt) {
            tacc[mt][nt] = MFMA16(mah[mt], xh_[nt], tacc[mt][nt]);
            tacc[mt][nt] = MFMA16(mah[mt], xl_[nt], tacc[mt][nt]);
            tacc[mt][nt] = MFMA16(mal[mt], xh_[nt], tacc[mt][nt]);
        }
    }
    #pragma unroll
    for (int mt = 0; mt < 2; ++mt)
    #pragma unroll
    for (int nt = 0; nt < 2; ++nt) {
        int u = qb + nt*16 + r;
        #pragma unroll
        for (int rp = 0; rp < 2; ++rp) {
            int c0 = 16*mt + 4*hi + 2*rp;
            float f0 = tacc[mt][nt][2*rp], f1 = tacc[mt][nt][2*rp+1];
            short h0 = bf16_trunc(f0), h1 = bf16_trunc(f1);
            short2v vh; vh[0] = h0; vh[1] = h1;
            *(short2v*)&Tt_h[u*TT_STRIDE + c0] = vh;
            short2v vl; vl[0] = bf16_trunc(f0 - bf16_tof(h0));
            vl[1] = bf16_trunc(f1 - bf16_tof(h1));
            *(short2v*)&Tt_l[u*TT_STRIDE + c0] = vl;
        }
    }
    __syncthreads();

    // S = X^T T (3-MFMA split); wave owns q-stripe [qb, qb+32)
    f32x4 sacc[2][8] = {};
    #pragma unroll
    for (int nt = 0; nt < 8; ++nt) {
        short8 th = *(const short8*)&Tt_h[(nt*16 + r)*TT_STRIDE + hi*8];
        short8 tl = *(const short8*)&Tt_l[(nt*16 + r)*TT_STRIDE + hi*8];
        #pragma unroll
        for (int qt = 0; qt < 2; ++qt) {
            sacc[qt][nt] = MFMA16(xh_[qt], th, sacc[qt][nt]);
            sacc[qt][nt] = MFMA16(xh_[qt], tl, sacc[qt][nt]);
            sacc[qt][nt] = MFMA16(xl_[qt], th, sacc[qt][nt]);
        }
    }
    // softmax over u (row q = qb+16qt+4hi+reg, col u = 16nt+r)
    float rls[2][4];
    #pragma unroll
    for (int qt = 0; qt < 2; ++qt)
    #pragma unroll
    for (int reg = 0; reg < 4; ++reg) {
        float m = sacc[qt][0][reg];
        #pragma unroll
        for (int nt = 1; nt < 8; ++nt) m = fmaxf(m, sacc[qt][nt][reg]);
        m = fmaxf(m, __shfl_xor(m, 1));
        m = fmaxf(m, __shfl_xor(m, 2));
        m = fmaxf(m, __shfl_xor(m, 4));
        m = fmaxf(m, __shfl_xor(m, 8));
        float s = 0.f;
        #pragma unroll
        for (int nt = 0; nt < 8; ++nt) {
            float e = __expf(sacc[qt][nt][reg] - m);
            sacc[qt][nt][reg] = e; s += e;
        }
        s += __shfl_xor(s, 1);
        s += __shfl_xor(s, 2);
        s += __shfl_xor(s, 4);
        s += __shfl_xor(s, 8);
        rls[qt][reg] = 1.f / s;
    }
    __syncthreads();                 // all Tt/Xf reads done -> overlay P
    #pragma unroll
    for (int qt = 0; qt < 2; ++qt)
    #pragma unroll
    for (int reg = 0; reg < 4; ++reg) {
        int q = qb + 16*qt + 4*hi + reg;
        float rl = rls[qt][reg];
        #pragma unroll
        for (int nt = 0; nt < 8; ++nt)
            P[q*P_STRIDE + nt*16 + r] = bf16_rtne(sacc[qt][nt][reg] * rl);
    }
    __syncthreads();

    // U = Xh * P^T : wave computes U[:, its 32 q]
    #pragma unroll
    for (int kt = 0; kt < 4; ++kt) {
        short8 xa[2], pb[2];
        #pragma unroll
        for (int mt = 0; mt < 2; ++mt)
            xa[mt] = *(const short8*)&Xh[(r + 16*mt)*XH_STRIDE + hi*8 + kt*32];
        #pragma unroll
        for (int nt = 0; nt < 2; ++nt)
            pb[nt] = *(const short8*)&P[(qb + 16*nt + r)*P_STRIDE + hi*8 + kt*32];
        #pragma unroll
        for (int mt = 0; mt < 2; ++mt)
        #pragma unroll
        for (int nt = 0; nt < 2; ++nt)
            uacc[mt][nt] = MFMA16(xa[mt], pb[nt], uacc[mt][nt]);
    }
}

// ---------------- W-axis: slice (d,h), coalesced ----------------------------
__global__ __launch_bounds__(256) void kw_kernel(const float* __restrict__ x,
        const short* __restrict__ ws, float* __restrict__ U) {
    __shared__ __align__(16) char Rr[R_BYTES];
    __shared__ __align__(16) short Xh[32*XH_STRIDE];
    float* Xf = (float*)Rr;
    short* Tt_h = (short*)(Rr + 16384);
    short* Tt_l = (short*)(Rr + 26624);
    short* P = (short*)Rr;
    int bid = xcd_swz(blockIdx.x, gridDim.x);
    int d = bid >> 7, h = bid & 127;
    int t = threadIdx.x;
    const int wv = t >> 6, l = t & 63, hi = l >> 4, r = l & 15;
    short8 mah[2], mal[2];
    #pragma unroll
    for (int mt = 0; mt < 2; ++mt) {
        mah[mt] = *(const short8*)&ws[(r + 16*mt)*32 + hi*8];
        mal[mt] = *(const short8*)&ws[1024 + (r + 16*mt)*32 + hi*8];
    }
    const float* xs = x + d*SD + h*SH;
    #pragma unroll
    for (int k = 0; k < 4; ++k) {
        int idx = t + k*256;
        int c = idx >> 5, u4 = idx & 31;
        float4 v = *(const float4*)&xs[c*SC + u4*4];
        *(float4*)&Xf[c*128 + u4*4] = v;
        short4v hv;
        hv[0] = bf16_rtne(v.x); hv[1] = bf16_rtne(v.y);
        hv[2] = bf16_rtne(v.z); hv[3] = bf16_rtne(v.w);
        *(short4v*)&Xh[c*XH_STRIDE + u4*4] = hv;
    }
    __syncthreads();
    f32x4 uacc[2][2] = {};
    slice_engine(Xf, mah, mal, Tt_h, Tt_l, P, Xh, uacc);
    float* Uo = U + d*SD + h*SH;
    #pragma unroll
    for (int mt = 0; mt < 2; ++mt)
    #pragma unroll
    for (int nt = 0; nt < 2; ++nt)
    #pragma unroll
    for (int reg = 0; reg < 4; ++reg) {
        int c = 16*mt + 4*hi + reg;
        int q = wv*32 + 16*nt + r;
        Uo[c*SC + q] = uacc[mt][nt][reg];   // first axis: plain store
    }
}

// ---------------- H-axis: one (d,w) slice per block -------------------------
__global__ __launch_bounds__(256) void kh_kernel(const float* __restrict__ x,
        const short* __restrict__ ws, float* __restrict__ U) {
    __shared__ __align__(16) char Rr[R_BYTES];
    __shared__ __align__(16) short Xh[32*XH_STRIDE];
    float* Xf = (float*)Rr;
    short* Tt_h = (short*)(Rr + 16384);
    short* Tt_l = (short*)(Rr + 26624);
    short* P = (short*)Rr;
    int bid = xcd_swz(blockIdx.x, gridDim.x);   // w-siblings share an XCD
    int d = bid >> 7, w = bid & 127;
    int t = threadIdx.x;
    const int wv = t >> 6, l = t & 63, hi = l >> 4, r = l & 15;
    short8 mah[2], mal[2];
    #pragma unroll
    for (int mt = 0; mt < 2; ++mt) {
        mah[mt] = *(const short8*)&ws[(r + 16*mt)*32 + hi*8];
        mal[mt] = *(const short8*)&ws[1024 + (r + 16*mt)*32 + hi*8];
    }
    const float* xs = x + d*SD + w;
    #pragma unroll
    for (int k = 0; k < 16; ++k) {
        int idx = t + k*256;
        int c = idx >> 7, g = idx & 127;
        float f = xs[c*SC + g*SH];
        Xf[c*128 + g] = f;
        Xh[c*XH_STRIDE + g] = bf16_rtne(f);
    }
    __syncthreads();
    f32x4 uacc[2][2] = {};
    slice_engine(Xf, mah, mal, Tt_h, Tt_l, P, Xh, uacc);
    float* Uo = U + d*SD + w;
    #pragma unroll
    for (int mt = 0; mt < 2; ++mt)
    #pragma unroll
    for (int nt = 0; nt < 2; ++nt)
    #pragma unroll
    for (int reg = 0; reg < 4; ++reg) {
        int c = 16*mt + 4*hi + reg;
        int q = wv*32 + 16*nt + r;     // q is the h row
        Uo[c*SC + q*SH] += uacc[mt][nt][reg];
    }
}

// ---------------- D-axis (L=32) MFMA engine + fused projection epilogue -----
// Block: 8 d-slices (h, w0..w0+7), 4 waves, wave wv owns slices {wv, wv+4}.
#define XJ 1152        // 32*36 shorts per slice plane
#define KD_TTS 40
#define KD_PS  36
__global__ __launch_bounds__(256, 2) void kd_kernel(const float* __restrict__ x,
        const short* __restrict__ ws, float* __restrict__ UO) {
    __shared__ __align__(16) short Xh[8*XJ], Xl[8*XJ];
    __shared__ __align__(16) char Rr[33792];
    short* Tt_h = (short*)Rr;             // [4][32][40]
    short* Tt_l = (short*)(Rr + 10240);   // [4][32][40]
    short* Pp   = (short*)(Rr + 20480);   // [4][32][36]
    float* u_lds = (float*)Rr;            // [32][264] after all slots consumed

    int bid = xcd_swz(blockIdx.x, gridDim.x);
    int h = bid >> 4, w0 = (bid & 15) * 8;
    int t = threadIdx.x;
    const int wv = t >> 6, l = t & 63, hi = l >> 4, r = l & 15;

    short8 mah[2], mal[2], pah[2], pal[2];
    #pragma unroll
    for (int mt = 0; mt < 2; ++mt) {
        mah[mt] = *(const short8*)&ws[(mt*16 + r)*32 + hi*8];
        mal[mt] = *(const short8*)&ws[1024 + (mt*16 + r)*32 + hi*8];
        pah[mt] = *(const short8*)&ws[2048 + (mt*16 + r)*32 + hi*8];
        pal[mt] = *(const short8*)&ws[3072 + (mt*16 + r)*32 + hi*8];
    }

    // stage x -> split-bf16 Xh/Xl [j][c][d]
    const float* xs = x + h*SH + w0;
    #pragma unroll
    for (int k = 0; k < 8; ++k) {
        int o = t + k*256;
        int j4 = o & 1, d = (o >> 1) & 31, c = o >> 6;
        float4 v = *(const float4*)(xs + c*SC + d*SD + j4*4);
        float fr[4] = {v.x, v.y, v.z, v.w};
        #pragma unroll
        for (int i = 0; i < 4; ++i) {
            short hh = bf16_trunc(fr[i]);
            Xh[((j4*4+i)*32 + c)*KD_PS + d] = hh;
            Xl[((j4*4+i)*32 + c)*KD_PS + d] = bf16_trunc(fr[i] - bf16_tof(hh));
        }
    }
    __syncthreads();                                  // (1) staging visible

    f32x4 uacc[2][2][2] = {};   // [pass][mt(c)][nt(d)]
    float4 upre[8];

    #pragma unroll
    for (int ps = 0; ps < 2; ++ps) {
        int j = ps*4 + wv;
        const short* Xhj = &Xh[j*XJ];
        const short* Xlj = &Xl[j*XJ];
        short8 xph[2], xpl[2];
        #pragma unroll
        for (int et = 0; et < 2; ++et)
        #pragma unroll
        for (int jj = 0; jj < 8; ++jj) {
            int c = hi*8 + jj;
            xph[et][jj] = Xhj[c*KD_PS + et*16 + r];
            xpl[et][jj] = Xlj[c*KD_PS + et*16 + r];
        }
        // T = M*X (3-MFMA split)
        f32x4 tacc[2][2] = {};
        #pragma unroll
        for (int et = 0; et < 2; ++et)
        #pragma unroll
        for (int mt = 0; mt < 2; ++mt) {
            tacc[mt][et] = MFMA16(mah[mt], xph[et], tacc[mt][et]);
            tacc[mt][et] = MFMA16(mah[mt], xpl[et], tacc[mt][et]);
            tacc[mt][et] = MFMA16(mal[mt], xph[et], tacc[mt][et]);
        }
        int tb = wv*32*KD_TTS;
        #pragma unroll
        for (int mt = 0; mt < 2; ++mt)
        #pragma unroll
        for (int et = 0; et < 2; ++et) {
            int e = et*16 + r;
            #pragma unroll
            for (int rp = 0; rp < 2; ++rp) {
                int c0 = mt*16 + hi*4 + rp*2;
                float f0 = tacc[mt][et][rp*2], f1 = tacc[mt][et][rp*2+1];
                short h0 = bf16_trunc(f0), h1 = bf16_trunc(f1);
                short2v vh; vh[0] = h0; vh[1] = h1;
                *(short2v*)&Tt_h[tb + e*KD_TTS + c0] = vh;
                short2v vl; vl[0] = bf16_trunc(f0 - bf16_tof(h0));
                vl[1] = bf16_trunc(f1 - bf16_tof(h1));
                *(short2v*)&Tt_l[tb + e*KD_TTS + c0] = vl;
            }
        }
        // S = X^T T (3-MFMA split), wave-private slot (no barrier)
        f32x4 sacc[2][2] = {};
        #pragma unroll
        for (int et = 0; et < 2; ++et) {
            short8 th = *(const short8*)&Tt_h[tb + (et*16 + r)*KD_TTS + hi*8];
            short8 tl = *(const short8*)&Tt_l[tb + (et*16 + r)*KD_TTS + hi*8];
            #pragma unroll
            for (int qt = 0; qt < 2; ++qt) {
                sacc[qt][et] = MFMA16(xph[qt], th, sacc[qt][et]);
                sacc[qt][et] = MFMA16(xph[qt], tl, sacc[qt][et]);
                sacc[qt][et] = MFMA16(xpl[qt], th, sacc[qt][et]);
            }
        }
        // softmax over e (row d = qt*16+hi*4+reg, col e = et*16+r)
        int pb = wv*32*KD_PS;
        #pragma unroll
        for (int qt = 0; qt < 2; ++qt)
        #pragma unroll
        for (int reg = 0; reg < 4; ++reg) {
            float m = fmaxf(sacc[qt][0][reg], sacc[qt][1][reg]);
            m = fmaxf(m, __shfl_xor(m, 1));
            m = fmaxf(m, __shfl_xor(m, 2));
            m = fmaxf(m, __shfl_xor(m, 4));
            m = fmaxf(m, __shfl_xor(m, 8));
            float e0 = __expf(sacc[qt][0][reg] - m);
            float e1 = __expf(sacc[qt][1][reg] - m);
            float s = e0 + e1;
            s += __shfl_xor(s, 1);
            s += __shfl_xor(s, 2);
            s += __shfl_xor(s, 4);
            s += __shfl_xor(s, 8);
            float rl = 1.f / s;
            int d = qt*16 + hi*4 + reg;
            Pp[pb + d*KD_PS + 0*16 + r] = bf16_rtne(e0 * rl);
            Pp[pb + d*KD_PS + 1*16 + r] = bf16_rtne(e1 * rl);
        }
        // U = X * P^T (bf16), own slot
        #pragma unroll
        for (int mt = 0; mt < 2; ++mt) {
            short8 xa = ld8_b64x2(&Xhj[(mt*16 + r)*KD_PS + hi*8]);
            #pragma unroll
            for (int nt = 0; nt < 2; ++nt) {
                short8 pbf = ld8_b64x2(&Pp[pb + (nt*16 + r)*KD_PS + hi*8]);
                uacc[ps][mt][nt] = MFMA16(xa, pbf, uacc[ps][mt][nt]);
            }
        }
        if (ps == 0) {    // prefetch UO (consumed post-barrier)
            #pragma unroll
            for (int k = 0; k < 8; ++k) {
                int o = t + k*256;
                int j4 = o & 1, d = (o >> 1) & 31, c = o >> 6;
                upre[k] = *(const float4*)(UO + c*SC + d*SD + h*SH + w0 + j4*4);
            }
        }
    }
    __syncthreads();                                  // (2) all Tt/Pp reads done
    #pragma unroll
    for (int k = 0; k < 8; ++k) {
        int o = t + k*256;
        int j4 = o & 1, d = (o >> 1) & 31, c = o >> 6;
        *(float4*)&u_lds[c*264 + d*8 + j4*4] = upre[k];
    }
    __syncthreads();                                  // (3) u_lds filled
    #pragma unroll
    for (int ps = 0; ps < 2; ++ps)
    #pragma unroll
    for (int mt = 0; mt < 2; ++mt)
    #pragma unroll
    for (int nt = 0; nt < 2; ++nt)
    #pragma unroll
    for (int reg = 0; reg < 4; ++reg) {
        int c = mt*16 + hi*4 + reg;
        u_lds[c*264 + (nt*16 + r)*8 + ps*4 + wv] += uacc[ps][mt][nt][reg];
    }
    __syncthreads();                                  // (4) u complete
    // epilogue: out = Ps*u + x, wave owns sites [wv*64, wv*64+64)
    f32x4 eacc[2][4] = {};
    #pragma unroll
    for (int nt = 0; nt < 4; ++nt) {
        short8 bh, bl;
        #pragma unroll
        for (int jj = 0; jj < 8; ++jj) {
            float f = u_lds[(hi*8 + jj)*264 + wv*64 + nt*16 + r];
            short hh = bf16_trunc(f);
            bh[jj] = hh; bl[jj] = bf16_trunc(f - bf16_tof(hh));
        }
        #pragma unroll
        for (int mt = 0; mt < 2; ++mt) {
            eacc[mt][nt] = MFMA16(pah[mt], bh, eacc[mt][nt]);
            eacc[mt][nt] = MFMA16(pah[mt], bl, eacc[mt][nt]);
            eacc[mt][nt] = MFMA16(pal[mt], bh, eacc[mt][nt]);
        }
    }
    #pragma unroll
    for (int mt = 0; mt < 2; ++mt)
    #pragma unroll
    for (int nt = 0; nt < 4; ++nt)
    #pragma unroll
    for (int reg = 0; reg < 4; ++reg) {
        int o = mt*16 + hi*4 + reg;
        int s = wv*64 + nt*16 + r;
        int addr = o*SC + (s >> 3)*SD + h*SH + w0 + (s & 7);
        UO[addr] = eacc[mt][nt][reg] + x[addr];
    }
}

extern "C" void kernel_launch(void* const* d_in, const int* in_sizes, int n_in,
                              void* d_out, int out_size, void* d_ws, size_t ws_size,
                              hipStream_t stream) {
    (void)in_sizes; (void)n_in; (void)out_size; (void)ws_size;
    const float* x  = (const float*)d_in[0];
    const float* Wq = (const float*)d_in[1];
    const float* Wk = (const float*)d_in[2];
    const float* Wv = (const float*)d_in[3];
    const float* Wo = (const float*)d_in[4];
    short* ws = (short*)d_ws;
    float* U = (float*)d_out;
    kinit_kernel<<<dim3(4), dim3(256), 0, stream>>>(Wq, Wk, Wv, Wo, ws);
    kw_kernel<<<dim3(4096), dim3(256), 0, stream>>>(x, ws, U);   // writes U
    kh_kernel<<<dim3(4096), dim3(256), 0, stream>>>(x, ws, U);   // U +=
    kd_kernel<<<dim3(2048), dim3(256), 0, stream>>>(x, ws, U);   // += proj + x
}

// Round 8
// 348.654 us; speedup vs baseline: 1.2353x; 1.2353x over previous
//
#include <hip/hip_runtime.h>

// Axial multi-dimensional self-attention, B=1, C=32, D=32, H=128, W=128, fp32.
// Algebra: S = X^T M X (M = scale*Wq^T*Wk), P = softmax_rows(S), U = X P^T,
//          out = (Wo Wv) (U_D + U_H + U_W) + x.
// kinit: M and Ps = Wo*Wv (split-bf16) into d_ws; blocks load fragments from L2.
// kw: 1-slice engine, float4 staging (3 blocks/CU).
// kh: 2-slice w-pair engine, float2 staging (validated R6 structure).
// kd: MFMA L=32 engine fused with projection epilogue + residual.

#define C_ 32
#define D_ 32
#define H_ 128
#define W_ 128
#define SC (D_*H_*W_)   // 524288
#define SD (H_*W_)      // 16384
#define SH (W_)         // 128
#define SCALE 0.17677669529663687f

typedef __attribute__((ext_vector_type(8))) short short8;   // 8 bf16 (4 VGPR)
typedef __attribute__((ext_vector_type(4))) short short4v;  // 4 bf16
typedef __attribute__((ext_vector_type(2))) short short2v;  // 2 bf16
typedef __attribute__((ext_vector_type(4))) float f32x4;

#define MFMA16(a,b,c) __builtin_amdgcn_mfma_f32_16x16x32_bf16(a,b,c,0,0,0)

__device__ __forceinline__ int xcd_swz(int bid, int nwg) {
    int chunk = nwg >> 3;
    return (bid & 7) * chunk + (bid >> 3);
}
__device__ __forceinline__ short bf16_trunc(float f) {
    return (short)(__float_as_uint(f) >> 16);
}
__device__ __forceinline__ short bf16_rtne(float f) {
    unsigned u = __float_as_uint(f);
    unsigned r = u + 0x7FFFu + ((u >> 16) & 1u);
    return (short)(r >> 16);
}
__device__ __forceinline__ float bf16_tof(short s) {
    return __uint_as_float(((unsigned)(unsigned short)s) << 16);
}
__device__ __forceinline__ short8 ld8_b64x2(const short* p) {
    short4v a = *(const short4v*)p;
    short4v b = *(const short4v*)(p + 4);
    short8 o;
    o[0]=a[0]; o[1]=a[1]; o[2]=a[2]; o[3]=a[3];
    o[4]=b[0]; o[5]=b[1]; o[6]=b[2]; o[7]=b[3];
    return o;
}

// ---------------- weight precompute: ws = [Mh|Ml|Ph|Pl], 1024 shorts each ---
__global__ __launch_bounds__(256) void kinit_kernel(
        const float* __restrict__ Wq, const float* __restrict__ Wk,
        const float* __restrict__ Wv, const float* __restrict__ Wo,
        short* __restrict__ ws) {
    int o = blockIdx.x * 256 + threadIdx.x;   // 4 blocks -> o in [0,1024)
    int a = o >> 5, b = o & 31;
    float m = 0.f, p = 0.f;
    #pragma unroll
    for (int k = 0; k < 32; ++k) {
        m += Wq[k*32+a] * Wk[k*32+b];   // M[a][b]
        p += Wo[a*32+k] * Wv[k*32+b];   // Ps[a][b]
    }
    m *= SCALE;
    short mh = bf16_trunc(m);
    ws[o]        = mh;
    ws[1024 + o] = bf16_trunc(m - bf16_tof(mh));
    short ph = bf16_trunc(p);
    ws[2048 + o] = ph;
    ws[3072 + o] = bf16_trunc(p - bf16_tof(ph));
}

// ---------------- MFMA slice engine: one L=128 slice (kw/kh) ----------------
// LDS R region (36864 B) = [Xf fp32 32x128 | Tt_h 128x40 | Tt_l 128x40],
// later overlaid by P bf16 [128][136] (34816 B). Xh bf16 [32][136] separate.
// Entry: Xf fp32 [c][u] and Xh bf16 [c][u] staged + barrier done.
#define TT_STRIDE 40
#define XH_STRIDE 136
#define P_STRIDE  136
#define R_BYTES   36864

__device__ __forceinline__ void slice_engine(
        const float* Xf, const short8 mah[2], const short8 mal[2],
        short* Tt_h, short* Tt_l, short* P, short* Xh,
        f32x4 uacc[2][2])
{
    const int t = threadIdx.x;
    const int wv = t >> 6, l = t & 63, hi = l >> 4, r = l & 15;
    const int qb = wv * 32;

    // split-bf16 X column fragments (T-B and S-A roles share one layout)
    short8 xh_[2], xl_[2];
    #pragma unroll
    for (int nt = 0; nt < 2; ++nt) {
        int u = qb + nt*16 + r;
        #pragma unroll
        for (int j = 0; j < 8; ++j) {
            float f = Xf[(hi*8 + j)*128 + u];
            short h = bf16_trunc(f);
            xh_[nt][j] = h; xl_[nt][j] = bf16_trunc(f - bf16_tof(h));
        }
    }

    // T = M*X (3-MFMA split); wave owns u in [qb, qb+32)
    f32x4 tacc[2][2] = {};
    #pragma unroll
    for (int nt = 0; nt < 2; ++nt) {
        #pragma unroll
        for (int mt = 0; mt < 2; ++mt) {
            tacc[mt][nt] = MFMA16(mah[mt], xh_[nt], tacc[mt][nt]);
            tacc[mt][nt] = MFMA16(mah[mt], xl_[nt], tacc[mt][nt]);
            tacc[mt][nt] = MFMA16(mal[mt], xh_[nt], tacc[mt][nt]);
        }
    }
    #pragma unroll
    for (int mt = 0; mt < 2; ++mt)
    #pragma unroll
    for (int nt = 0; nt < 2; ++nt) {
        int u = qb + nt*16 + r;
        #pragma unroll
        for (int rp = 0; rp < 2; ++rp) {
            int c0 = 16*mt + 4*hi + 2*rp;
            float f0 = tacc[mt][nt][2*rp], f1 = tacc[mt][nt][2*rp+1];
            short h0 = bf16_trunc(f0), h1 = bf16_trunc(f1);
            short2v vh; vh[0] = h0; vh[1] = h1;
            *(short2v*)&Tt_h[u*TT_STRIDE + c0] = vh;
            short2v vl; vl[0] = bf16_trunc(f0 - bf16_tof(h0));
            vl[1] = bf16_trunc(f1 - bf16_tof(h1));
            *(short2v*)&Tt_l[u*TT_STRIDE + c0] = vl;
        }
    }
    __syncthreads();

    // S = X^T T (3-MFMA split); wave owns q-stripe [qb, qb+32)
    f32x4 sacc[2][8] = {};
    #pragma unroll
    for (int nt = 0; nt < 8; ++nt) {
        short8 th = *(const short8*)&Tt_h[(nt*16 + r)*TT_STRIDE + hi*8];
        short8 tl = *(const short8*)&Tt_l[(nt*16 + r)*TT_STRIDE + hi*8];
        #pragma unroll
        for (int qt = 0; qt < 2; ++qt) {
            sacc[qt][nt] = MFMA16(xh_[qt], th, sacc[qt][nt]);
            sacc[qt][nt] = MFMA16(xh_[qt], tl, sacc[qt][nt]);
            sacc[qt][nt] = MFMA16(xl_[qt], th, sacc[qt][nt]);
        }
    }
    // softmax over u (row q = qb+16qt+4hi+reg, col u = 16nt+r)
    float rls[2][4];
    #pragma unroll
    for (int qt = 0; qt < 2; ++qt)
    #pragma unroll
    for (int reg = 0; reg < 4; ++reg) {
        float m = sacc[qt][0][reg];
        #pragma unroll
        for (int nt = 1; nt < 8; ++nt) m = fmaxf(m, sacc[qt][nt][reg]);
        m = fmaxf(m, __shfl_xor(m, 1));
        m = fmaxf(m, __shfl_xor(m, 2));
        m = fmaxf(m, __shfl_xor(m, 4));
        m = fmaxf(m, __shfl_xor(m, 8));
        float s = 0.f;
        #pragma unroll
        for (int nt = 0; nt < 8; ++nt) {
            float e = __expf(sacc[qt][nt][reg] - m);
            sacc[qt][nt][reg] = e; s += e;
        }
        s += __shfl_xor(s, 1);
        s += __shfl_xor(s, 2);
        s += __shfl_xor(s, 4);
        s += __shfl_xor(s, 8);
        rls[qt][reg] = 1.f / s;
    }
    __syncthreads();                 // all Tt/Xf reads done -> overlay P
    #pragma unroll
    for (int qt = 0; qt < 2; ++qt)
    #pragma unroll
    for (int reg = 0; reg < 4; ++reg) {
        int q = qb + 16*qt + 4*hi + reg;
        float rl = rls[qt][reg];
        #pragma unroll
        for (int nt = 0; nt < 8; ++nt)
            P[q*P_STRIDE + nt*16 + r] = bf16_rtne(sacc[qt][nt][reg] * rl);
    }
    __syncthreads();

    // U = Xh * P^T : wave computes U[:, its 32 q]
    #pragma unroll
    for (int kt = 0; kt < 4; ++kt) {
        short8 xa[2], pb[2];
        #pragma unroll
        for (int mt = 0; mt < 2; ++mt)
            xa[mt] = *(const short8*)&Xh[(r + 16*mt)*XH_STRIDE + hi*8 + kt*32];
        #pragma unroll
        for (int nt = 0; nt < 2; ++nt)
            pb[nt] = *(const short8*)&P[(qb + 16*nt + r)*P_STRIDE + hi*8 + kt*32];
        #pragma unroll
        for (int mt = 0; mt < 2; ++mt)
        #pragma unroll
        for (int nt = 0; nt < 2; ++nt)
            uacc[mt][nt] = MFMA16(xa[mt], pb[nt], uacc[mt][nt]);
    }
}

// ---------------- W-axis: slice (d,h), coalesced ----------------------------
__global__ __launch_bounds__(256) void kw_kernel(const float* __restrict__ x,
        const short* __restrict__ ws, float* __restrict__ U) {
    __shared__ __align__(16) char Rr[R_BYTES];
    __shared__ __align__(16) short Xh[32*XH_STRIDE];
    float* Xf = (float*)Rr;
    short* Tt_h = (short*)(Rr + 16384);
    short* Tt_l = (short*)(Rr + 26624);
    short* P = (short*)Rr;
    int bid = xcd_swz(blockIdx.x, gridDim.x);
    int d = bid >> 7, h = bid & 127;
    int t = threadIdx.x;
    const int wv = t >> 6, l = t & 63, hi = l >> 4, r = l & 15;
    short8 mah[2], mal[2];
    #pragma unroll
    for (int mt = 0; mt < 2; ++mt) {
        mah[mt] = *(const short8*)&ws[(r + 16*mt)*32 + hi*8];
        mal[mt] = *(const short8*)&ws[1024 + (r + 16*mt)*32 + hi*8];
    }
    const float* xs = x + d*SD + h*SH;
    #pragma unroll
    for (int k = 0; k < 4; ++k) {
        int idx = t + k*256;
        int c = idx >> 5, u4 = idx & 31;
        float4 v = *(const float4*)&xs[c*SC + u4*4];
        *(float4*)&Xf[c*128 + u4*4] = v;
        short4v hv;
        hv[0] = bf16_rtne(v.x); hv[1] = bf16_rtne(v.y);
        hv[2] = bf16_rtne(v.z); hv[3] = bf16_rtne(v.w);
        *(short4v*)&Xh[c*XH_STRIDE + u4*4] = hv;
    }
    __syncthreads();
    f32x4 uacc[2][2] = {};
    slice_engine(Xf, mah, mal, Tt_h, Tt_l, P, Xh, uacc);
    float* Uo = U + d*SD + h*SH;
    #pragma unroll
    for (int mt = 0; mt < 2; ++mt)
    #pragma unroll
    for (int nt = 0; nt < 2; ++nt)
    #pragma unroll
    for (int reg = 0; reg < 4; ++reg) {
        int c = 16*mt + 4*hi + reg;
        int q = wv*32 + 16*nt + r;
        Uo[c*SC + q] = uacc[mt][nt][reg];   // first axis: plain store
    }
}

// ---------------- H-axis: slices (d, w-pair), float2 staging ----------------
__global__ __launch_bounds__(256) void kh_kernel(const float* __restrict__ x,
        const short* __restrict__ ws, float* __restrict__ U) {
    __shared__ __align__(16) char Rr[R_BYTES];
    __shared__ __align__(16) float Xf1[32*128];
    __shared__ __align__(16) short Xh[32*XH_STRIDE];
    float* Xf0 = (float*)Rr;
    short* Tt_h = (short*)(Rr + 16384);
    short* Tt_l = (short*)(Rr + 26624);
    short* P = (short*)Rr;
    int bid = xcd_swz(blockIdx.x, gridDim.x);   // w-siblings share an XCD
    int d = bid >> 6, w0 = (bid & 63) * 2;
    int t = threadIdx.x;
    const int wv = t >> 6, l = t & 63, hi = l >> 4, r = l & 15;
    short8 mah[2], mal[2];
    #pragma unroll
    for (int mt = 0; mt < 2; ++mt) {
        mah[mt] = *(const short8*)&ws[(r + 16*mt)*32 + hi*8];
        mal[mt] = *(const short8*)&ws[1024 + (r + 16*mt)*32 + hi*8];
    }
    const float* xs = x + d*SD + w0;
    #pragma unroll
    for (int k = 0; k < 16; ++k) {
        int idx = t + k*256;
        int c = idx >> 7, g = idx & 127;
        float2 v = *(const float2*)&xs[c*SC + g*SH];
        Xf0[c*128+g] = v.x;
        Xf1[c*128+g] = v.y;
        Xh[c*XH_STRIDE+g] = bf16_rtne(v.x);   // Xh for slice 0
    }
    __syncthreads();
    f32x4 u0[2][2] = {}, u1[2][2] = {};
    slice_engine(Xf0, mah, mal, Tt_h, Tt_l, P, Xh, u0);
    __syncthreads();   // all P/Xh reads of slice 0 done
    // rebuild Xh from Xf1 (visible by engine's first internal barrier)
    #pragma unroll
    for (int k = 0; k < 8; ++k) {
        int idx = t + k*256;
        int g2 = idx & 63, c = idx >> 6;
        float2 v = *(const float2*)&Xf1[c*128 + g2*2];
        short2v hv; hv[0] = bf16_rtne(v.x); hv[1] = bf16_rtne(v.y);
        *(short2v*)&Xh[c*XH_STRIDE + g2*2] = hv;
    }
    slice_engine(Xf1, mah, mal, Tt_h, Tt_l, P, Xh, u1);
    float* Uo = U + d*SD + w0;
    #pragma unroll
    for (int mt = 0; mt < 2; ++mt)
    #pragma unroll
    for (int nt = 0; nt < 2; ++nt)
    #pragma unroll
    for (int reg = 0; reg < 4; ++reg) {
        int c = 16*mt + 4*hi + reg;
        int q = wv*32 + 16*nt + r;     // q is the h row
        float2* p = (float2*)&Uo[c*SC + q*SH];
        float2 v = *p;
        v.x += u0[mt][nt][reg];
        v.y += u1[mt][nt][reg];
        *p = v;
    }
}

// ---------------- D-axis (L=32) MFMA engine + fused projection epilogue -----
// Block: 8 d-slices (h, w0..w0+7), 4 waves, wave wv owns slices {wv, wv+4}.
#define XJ 1152        // 32*36 shorts per slice plane
#define KD_TTS 40
#define KD_PS  36
__global__ __launch_bounds__(256, 2) void kd_kernel(const float* __restrict__ x,
        const short* __restrict__ ws, float* __restrict__ UO) {
    __shared__ __align__(16) short Xh[8*XJ], Xl[8*XJ];
    __shared__ __align__(16) char Rr[33792];
    short* Tt_h = (short*)Rr;             // [4][32][40]
    short* Tt_l = (short*)(Rr + 10240);   // [4][32][40]
    short* Pp   = (short*)(Rr + 20480);   // [4][32][36]
    float* u_lds = (float*)Rr;            // [32][264] after all slots consumed

    int bid = xcd_swz(blockIdx.x, gridDim.x);
    int h = bid >> 4, w0 = (bid & 15) * 8;
    int t = threadIdx.x;
    const int wv = t >> 6, l = t & 63, hi = l >> 4, r = l & 15;

    short8 mah[2], mal[2], pah[2], pal[2];
    #pragma unroll
    for (int mt = 0; mt < 2; ++mt) {
        mah[mt] = *(const short8*)&ws[(mt*16 + r)*32 + hi*8];
        mal[mt] = *(const short8*)&ws[1024 + (mt*16 + r)*32 + hi*8];
        pah[mt] = *(const short8*)&ws[2048 + (mt*16 + r)*32 + hi*8];
        pal[mt] = *(const short8*)&ws[3072 + (mt*16 + r)*32 + hi*8];
    }

    // stage x -> split-bf16 Xh/Xl [j][c][d]
    const float* xs = x + h*SH + w0;
    #pragma unroll
    for (int k = 0; k < 8; ++k) {
        int o = t + k*256;
        int j4 = o & 1, d = (o >> 1) & 31, c = o >> 6;
        float4 v = *(const float4*)(xs + c*SC + d*SD + j4*4);
        float fr[4] = {v.x, v.y, v.z, v.w};
        #pragma unroll
        for (int i = 0; i < 4; ++i) {
            short hh = bf16_trunc(fr[i]);
            Xh[((j4*4+i)*32 + c)*KD_PS + d] = hh;
            Xl[((j4*4+i)*32 + c)*KD_PS + d] = bf16_trunc(fr[i] - bf16_tof(hh));
        }
    }
    __syncthreads();                                  // (1) staging visible

    f32x4 uacc[2][2][2] = {};   // [pass][mt(c)][nt(d)]
    float4 upre[8];

    #pragma unroll
    for (int ps = 0; ps < 2; ++ps) {
        int j = ps*4 + wv;
        const short* Xhj = &Xh[j*XJ];
        const short* Xlj = &Xl[j*XJ];
        short8 xph[2], xpl[2];
        #pragma unroll
        for (int et = 0; et < 2; ++et)
        #pragma unroll
        for (int jj = 0; jj < 8; ++jj) {
            int c = hi*8 + jj;
            xph[et][jj] = Xhj[c*KD_PS + et*16 + r];
            xpl[et][jj] = Xlj[c*KD_PS + et*16 + r];
        }
        // T = M*X (3-MFMA split)
        f32x4 tacc[2][2] = {};
        #pragma unroll
        for (int et = 0; et < 2; ++et)
        #pragma unroll
        for (int mt = 0; mt < 2; ++mt) {
            tacc[mt][et] = MFMA16(mah[mt], xph[et], tacc[mt][et]);
            tacc[mt][et] = MFMA16(mah[mt], xpl[et], tacc[mt][et]);
            tacc[mt][et] = MFMA16(mal[mt], xph[et], tacc[mt][et]);
        }
        int tb = wv*32*KD_TTS;
        #pragma unroll
        for (int mt = 0; mt < 2; ++mt)
        #pragma unroll
        for (int et = 0; et < 2; ++et) {
            int e = et*16 + r;
            #pragma unroll
            for (int rp = 0; rp < 2; ++rp) {
                int c0 = mt*16 + hi*4 + rp*2;
                float f0 = tacc[mt][et][rp*2], f1 = tacc[mt][et][rp*2+1];
                short h0 = bf16_trunc(f0), h1 = bf16_trunc(f1);
                short2v vh; vh[0] = h0; vh[1] = h1;
                *(short2v*)&Tt_h[tb + e*KD_TTS + c0] = vh;
                short2v vl; vl[0] = bf16_trunc(f0 - bf16_tof(h0));
                vl[1] = bf16_trunc(f1 - bf16_tof(h1));
                *(short2v*)&Tt_l[tb + e*KD_TTS + c0] = vl;
            }
        }
        // S = X^T T (3-MFMA split), wave-private slot (no barrier)
        f32x4 sacc[2][2] = {};
        #pragma unroll
        for (int et = 0; et < 2; ++et) {
            short8 th = *(const short8*)&Tt_h[tb + (et*16 + r)*KD_TTS + hi*8];
            short8 tl = *(const short8*)&Tt_l[tb + (et*16 + r)*KD_TTS + hi*8];
            #pragma unroll
            for (int qt = 0; qt < 2; ++qt) {
                sacc[qt][et] = MFMA16(xph[qt], th, sacc[qt][et]);
                sacc[qt][et] = MFMA16(xph[qt], tl, sacc[qt][et]);
                sacc[qt][et] = MFMA16(xpl[qt], th, sacc[qt][et]);
            }
        }
        // softmax over e (row d = qt*16+hi*4+reg, col e = et*16+r)
        int pb = wv*32*KD_PS;
        #pragma unroll
        for (int qt = 0; qt < 2; ++qt)
        #pragma unroll
        for (int reg = 0; reg < 4; ++reg) {
            float m = fmaxf(sacc[qt][0][reg], sacc[qt][1][reg]);
            m = fmaxf(m, __shfl_xor(m, 1));
            m = fmaxf(m, __shfl_xor(m, 2));
            m = fmaxf(m, __shfl_xor(m, 4));
            m = fmaxf(m, __shfl_xor(m, 8));
            float e0 = __expf(sacc[qt][0][reg] - m);
            float e1 = __expf(sacc[qt][1][reg] - m);
            float s = e0 + e1;
            s += __shfl_xor(s, 1);
            s += __shfl_xor(s, 2);
            s += __shfl_xor(s, 4);
            s += __shfl_xor(s, 8);
            float rl = 1.f / s;
            int d = qt*16 + hi*4 + reg;
            Pp[pb + d*KD_PS + 0*16 + r] = bf16_rtne(e0 * rl);
            Pp[pb + d*KD_PS + 1*16 + r] = bf16_rtne(e1 * rl);
        }
        // U = X * P^T (bf16), own slot
        #pragma unroll
        for (int mt = 0; mt < 2; ++mt) {
            short8 xa = ld8_b64x2(&Xhj[(mt*16 + r)*KD_PS + hi*8]);
            #pragma unroll
            for (int nt = 0; nt < 2; ++nt) {
                short8 pbf = ld8_b64x2(&Pp[pb + (nt*16 + r)*KD_PS + hi*8]);
                uacc[ps][mt][nt] = MFMA16(xa, pbf, uacc[ps][mt][nt]);
            }
        }
        if (ps == 0) {    // prefetch UO (consumed post-barrier)
            #pragma unroll
            for (int k = 0; k < 8; ++k) {
                int o = t + k*256;
                int j4 = o & 1, d = (o >> 1) & 31, c = o >> 6;
                upre[k] = *(const float4*)(UO + c*SC + d*SD + h*SH + w0 + j4*4);
            }
        }
    }
    __syncthreads();                                  // (2) all Tt/Pp reads done
    #pragma unroll
    for (int k = 0; k < 8; ++k) {
        int o = t + k*256;
        int j4 = o & 1, d = (o >> 1) & 31, c = o >> 6;
        *(float4*)&u_lds[c*264 + d*8 + j4*4] = upre[k];
    }
    __syncthreads();                                  // (3) u_lds filled
    #pragma unroll
    for (int ps = 0; ps < 2; ++ps)
    #pragma unroll
    for (int mt = 0; mt < 2; ++mt)
    #pragma unroll
    for (int nt = 0; nt < 2; ++nt)
    #pragma unroll
    for (int reg = 0; reg < 4; ++reg) {
        int c = mt*16 + hi*4 + reg;
        u_lds[c*264 + (nt*16 + r)*8 + ps*4 + wv] += uacc[ps][mt][nt][reg];
    }
    __syncthreads();                                  // (4) u complete
    // epilogue: out = Ps*u + x, wave owns sites [wv*64, wv*64+64)
    f32x4 eacc[2][4] = {};
    #pragma unroll
    for (int nt = 0; nt < 4; ++nt) {
        short8 bh, bl;
        #pragma unroll
        for (int jj = 0; jj < 8; ++jj) {
            float f = u_lds[(hi*8 + jj)*264 + wv*64 + nt*16 + r];
            short hh = bf16_trunc(f);
            bh[jj] = hh; bl[jj] = bf16_trunc(f - bf16_tof(hh));
        }
        #pragma unroll
        for (int mt = 0; mt < 2; ++mt) {
            eacc[mt][nt] = MFMA16(pah[mt], bh, eacc[mt][nt]);
            eacc[mt][nt] = MFMA16(pah[mt], bl, eacc[mt][nt]);
            eacc[mt][nt] = MFMA16(pal[mt], bh, eacc[mt][nt]);
        }
    }
    #pragma unroll
    for (int mt = 0; mt < 2; ++mt)
    #pragma unroll
    for (int nt = 0; nt < 4; ++nt)
    #pragma unroll
    for (int reg = 0; reg < 4; ++reg) {
        int o = mt*16 + hi*4 + reg;
        int s = wv*64 + nt*16 + r;
        int addr = o*SC + (s >> 3)*SD + h*SH + w0 + (s & 7);
        UO[addr] = eacc[mt][nt][reg] + x[addr];
    }
}

extern "C" void kernel_launch(void* const* d_in, const int* in_sizes, int n_in,
                              void* d_out, int out_size, void* d_ws, size_t ws_size,
                              hipStream_t stream) {
    (void)in_sizes; (void)n_in; (void)out_size; (void)ws_size;
    const float* x  = (const float*)d_in[0];
    const float* Wq = (const float*)d_in[1];
    const float* Wk = (const float*)d_in[2];
    const float* Wv = (const float*)d_in[3];
    const float* Wo = (const float*)d_in[4];
    short* ws = (short*)d_ws;
    float* U = (float*)d_out;
    kinit_kernel<<<dim3(4), dim3(256), 0, stream>>>(Wq, Wk, Wv, Wo, ws);
    kw_kernel<<<dim3(4096), dim3(256), 0, stream>>>(x, ws, U);   // writes U
    kh_kernel<<<dim3(2048), dim3(256), 0, stream>>>(x, ws, U);   // U +=
    kd_kernel<<<dim3(2048), dim3(256), 0, stream>>>(x, ws, U);   // += proj + x
}